// Round 15
// baseline (313.781 us; speedup 1.0000x reference)
//
#include <hip/hip_runtime.h>

typedef unsigned short u16;
typedef __attribute__((ext_vector_type(8))) short short8;
typedef __attribute__((ext_vector_type(4))) float f32x4;
typedef __attribute__((ext_vector_type(2))) float f32x2;

#define N_AGENTS 131072
#define HID 128
#define FUT 12
#define OBS 8

constexpr int AG = 16;             // 16-agent tiles per block -> 256 agents/block
#define NEG_K  (-1.4426950408889634f)   // -log2(e)
#define NEG_2K (-2.8853900817779268f)   // -2*log2(e)

__device__ __forceinline__ u16 f2bf(float f) {   // RNE (setup only)
    union { float f; unsigned int i; } v; v.f = f;
    unsigned int u = v.i;
    return (u16)((u + 0x7fffu + ((u >> 16) & 1u)) >> 16);
}
__device__ __forceinline__ float bexp2(float x) {
#if __has_builtin(__builtin_amdgcn_exp2f)
    return __builtin_amdgcn_exp2f(x);
#else
    float r; asm("v_exp_f32 %0, %1" : "=v"(r) : "v"(x)); return r;
#endif
}
__device__ __forceinline__ float brcp(float x) {
#if __has_builtin(__builtin_amdgcn_rcpf)
    return __builtin_amdgcn_rcpf(x);
#else
    float r; asm("v_rcp_f32 %0, %1" : "=v"(r) : "v"(x)); return r;
#endif
}
__device__ __forceinline__ unsigned cvtpk(float lo, float hi) {  // 2x f32 -> packed bf16 (RNE)
    unsigned r; asm("v_cvt_pk_bf16_f32 %0, %1, %2" : "=v"(r) : "v"(lo), "v"(hi)); return r;
}

__launch_bounds__(512, 4)
__global__ void lstm_dec_kernel(const float* __restrict__ obs,
                                const float* __restrict__ h0g,
                                const float* __restrict__ Wih,
                                const float* __restrict__ Whh,
                                const float* __restrict__ bih,
                                const float* __restrict__ bhh,
                                const float* __restrict__ Wout,
                                const float* __restrict__ bout,
                                float* __restrict__ dout)
{
    // 80,000 B total -> two blocks fit in 160 KiB LDS
    __shared__ short8 wgo[2][8][4][64];   // 64 KB: g,o-gate W_eff frags [nt-2][wv][kf][lane]
    __shared__ short8 hb[2][16][17];      // 8.7 KB: h double-buffer, 272B rows
    __shared__ short8 outb_lds[4][64];    // 4 KB: W_out B-frags
    __shared__ float  xt[16][2];          // 128 B
    __shared__ float  ot[FUT][16][2];     // 1.5 KB staged outputs

    const int tid  = threadIdx.x;
    const int lane = tid & 63;
    const int wv   = tid >> 6;      // wave 0..7, owns gate cols {nt*128 + wv*16 + r}
    const int r    = lane & 15;
    const int kb   = lane >> 4;

    const float bout0 = bout[0];
    const float bout1 = bout[1];
    const float bo_sc = (r == 0) ? bout0 : ((r == 1) ? bout1 : 0.0f);

    // scaled effective bias (added in-cell), 4 VGPR
    float beff[4];
#pragma unroll
    for (int nt = 0; nt < 4; ++nt) {
        const float gs = (nt == 2) ? NEG_2K : NEG_K;
        int c = nt * HID + wv * 16 + r;
        beff[nt] = (bih[c] + bhh[c] + Wih[c * 2 + 0] * bout0 + Wih[c * 2 + 1] * bout1) * gs;
    }

    // W_eff = (W_hh + W_ih @ W_out) * gsc: nt=0,1 (i,f) -> registers (32 VGPR),
    // nt=2,3 (g,o) -> LDS (per-wave private region, conflict-free b128 reads)
    short8 bfr[2][4];
#pragma unroll
    for (int kf = 0; kf < 4; ++kf) {
        const int k0 = kf * 32 + kb * 8;
        float wo0[8], wo1[8];
#pragma unroll
        for (int j = 0; j < 8; ++j) {
            wo0[j] = Wout[0 * HID + k0 + j];
            wo1[j] = Wout[1 * HID + k0 + j];
        }
        if (wv == 0) {   // out-projection B-frags
            short8 ob;
#pragma unroll
            for (int j = 0; j < 8; ++j) {
                float sel = (r == 0) ? wo0[j] : ((r == 1) ? wo1[j] : 0.0f);
                ob[j] = (short)f2bf(sel);
            }
            outb_lds[kf][lane] = ob;
        }
#pragma unroll
        for (int nt = 0; nt < 4; ++nt) {
            const float gs = (nt == 2) ? NEG_2K : NEG_K;
            int c = nt * HID + wv * 16 + r;
            float s0 = Wih[c * 2 + 0] * gs;
            float s1 = Wih[c * 2 + 1] * gs;
            short8 tt;
#pragma unroll
            for (int j = 0; j < 8; ++j) {
                float f = Whh[(size_t)c * HID + k0 + j] * gs
                        + s0 * wo0[j] + s1 * wo1[j];
                tt[j] = (short)f2bf(f);
            }
            if (nt < 2) bfr[nt][kf] = tt;
            else        wgo[nt - 2][wv][kf][lane] = tt;
        }
    }

// ---- macros ----
#define GATES(rb)                                                    \
    _Pragma("unroll")                                                \
    for (int kf = 0; kf < 4; ++kf)                                   \
        af[kf] = hb[rb][r][kf * 4 + kb];                             \
    {                                                                \
        const f32x4 z4 = {0.f, 0.f, 0.f, 0.f};                       \
        acc[0] = __builtin_amdgcn_mfma_f32_16x16x32_bf16(af[0], bfr[0][0], z4, 0, 0, 0); \
        acc[1] = __builtin_amdgcn_mfma_f32_16x16x32_bf16(af[0], bfr[1][0], z4, 0, 0, 0); \
        acc[2] = __builtin_amdgcn_mfma_f32_16x16x32_bf16(af[0], wgo[0][wv][0][lane], z4, 0, 0, 0); \
        acc[3] = __builtin_amdgcn_mfma_f32_16x16x32_bf16(af[0], wgo[1][wv][0][lane], z4, 0, 0, 0); \
        _Pragma("unroll")                                            \
        for (int kf = 1; kf < 4; ++kf) {                             \
            acc[0] = __builtin_amdgcn_mfma_f32_16x16x32_bf16(af[kf], bfr[0][kf], acc[0], 0, 0, 0); \
            acc[1] = __builtin_amdgcn_mfma_f32_16x16x32_bf16(af[kf], bfr[1][kf], acc[1], 0, 0, 0); \
            acc[2] = __builtin_amdgcn_mfma_f32_16x16x32_bf16(af[kf], wgo[0][wv][kf][lane], acc[2], 0, 0, 0); \
            acc[3] = __builtin_amdgcn_mfma_f32_16x16x32_bf16(af[kf], wgo[1][wv][kf][lane], acc[3], 0, 0, 0); \
        }                                                            \
    }

// out projection on wave 0 only; reads hb itself (works in step-12 phase too)
#define OUT_TILE(rb, dst_expr)                                       \
    if (wv == 0) {                                                   \
        const f32x4 z4o = {0.f, 0.f, 0.f, 0.f};                      \
        short8 t0 = hb[rb][r][kb];                                   \
        f32x4 oacc = __builtin_amdgcn_mfma_f32_16x16x32_bf16(        \
            t0, outb_lds[0][lane], z4o, 0, 0, 0);                    \
        t0 = hb[rb][r][4 + kb];                                      \
        oacc = __builtin_amdgcn_mfma_f32_16x16x32_bf16(              \
            t0, outb_lds[1][lane], oacc, 0, 0, 0);                   \
        t0 = hb[rb][r][8 + kb];                                      \
        oacc = __builtin_amdgcn_mfma_f32_16x16x32_bf16(              \
            t0, outb_lds[2][lane], oacc, 0, 0, 0);                   \
        t0 = hb[rb][r][12 + kb];                                     \
        oacc = __builtin_amdgcn_mfma_f32_16x16x32_bf16(              \
            t0, outb_lds[3][lane], oacc, 0, 0, 0);                   \
        if (r < 2) {                                                 \
            _Pragma("unroll")                                        \
            for (int q = 0; q < 4; ++q)                              \
                (dst_expr)[kb * 4 + q][r] = oacc[q] + bo_sc;         \
        }                                                            \
    }

// step-0 exact correction (obs/Wih L2-hot, once per tile)
#define CORR()                                                       \
    {                                                                \
        float dx0[4], dx1[4];                                        \
        _Pragma("unroll")                                            \
        for (int q = 0; q < 4; ++q) {                                \
            int ag = A0 + kb * 4 + q;                                \
            dx0[q] = obs[((size_t)(OBS - 1) * N_AGENTS + ag) * 2 + 0] - xt[kb * 4 + q][0]; \
            dx1[q] = obs[((size_t)(OBS - 1) * N_AGENTS + ag) * 2 + 1] - xt[kb * 4 + q][1]; \
        }                                                            \
        _Pragma("unroll")                                            \
        for (int nt = 0; nt < 4; ++nt) {                             \
            const float gs = (nt == 2) ? NEG_2K : NEG_K;             \
            int c = nt * HID + wv * 16 + r;                          \
            float w0s = Wih[c * 2 + 0] * gs;                         \
            float w1s = Wih[c * 2 + 1] * gs;                         \
            _Pragma("unroll")                                        \
            for (int q = 0; q < 4; ++q)                              \
                acc[nt][q] += dx0[q] * w0s + dx1[q] * w1s;           \
        }                                                            \
    }

// packed pair-cell (q pair), math identical to R7..R14
#define CELLP(qa, qb)                                                \
    {                                                                \
        f32x2 Ei = {bexp2(acc[0][qa] + beff[0]), bexp2(acc[0][qb] + beff[0])}; \
        f32x2 Ef = {bexp2(acc[1][qa] + beff[1]), bexp2(acc[1][qb] + beff[1])}; \
        f32x2 Gg = {bexp2(acc[2][qa] + beff[2]), bexp2(acc[2][qb] + beff[2])}; \
        f32x2 Eo = {bexp2(acc[3][qa] + beff[3]), bexp2(acc[3][qb] + beff[3])}; \
        f32x2 c2 = {cf[qa], cf[qb]};                                 \
        f32x2 t1 = 1.0f + Ei;                                        \
        f32x2 t2 = 1.0f + Gg;                                        \
        f32x2 t3 = 1.0f + Ef;                                        \
        f32x2 t12 = t1 * t2;                                         \
        f32x2 num = t12 * c2 + t3 * (1.0f - Gg);                     \
        f32x2 den = t12 * t3;                                        \
        f32x2 R1 = {brcp(den.x), brcp(den.y)};                       \
        f32x2 cn = num * R1;                                         \
        cf[qa] = cn.x; cf[qb] = cn.y;                                \
        f32x2 ga = NEG_2K * cn;                                      \
        f32x2 Gc = {bexp2(ga.x), bexp2(ga.y)};                       \
        f32x2 u1 = (1.0f + Eo) * (1.0f + Gc);                        \
        f32x2 R2 = {brcp(u1.x), brcp(u1.y)};                         \
        f32x2 hv = (1.0f - Gc) * R2;                                 \
        unsigned pk = cvtpk(hv.x, hv.y);                             \
        hbase[(kb * 4 + qa) * 136 + wv * 16 + r] = (u16)pk;          \
        hbase[(kb * 4 + qb) * 136 + wv * 16 + r] = (u16)(pk >> 16);  \
    }

#define ACTIV(wb)                                                    \
    {                                                                \
        u16* hbase = (u16*)&hb[wb][0][0];                            \
        CELLP(0, 1) CELLP(2, 3)                                      \
    }

#pragma unroll 1
    for (int t = 0; t < AG; ++t) {
        const int A0 = (blockIdx.x * AG + t) * 16;

        // cooperative h0 preload -> hb[1]: 16 rows, 32 threads/row, 4 f32 each
        {
            int row = tid >> 5;
            int c4  = (tid & 31) * 4;
            const float* hp = h0g + (size_t)(A0 + row) * HID + c4;
            f32x4 v = *(const f32x4*)hp;
            unsigned* dst = (unsigned*)&hb[1][row][0] + (tid & 31) * 2;
            dst[0] = cvtpk(v[0], v[1]);
            dst[1] = cvtpk(v[2], v[3]);
        }
        f32x4 cf = {0.f, 0.f, 0.f, 0.f};
        f32x4 acc[4];
        short8 af[4];
        __syncthreads();

        // ---------------- step 0 ----------------
        GATES(1)
        OUT_TILE(1, xt)
        __syncthreads();   // x~0 visible
        CORR()
        ACTIV(0)
        __syncthreads();   // h(0) visible

        // ---------------- steps 1..11 ----------------
#pragma unroll 1
        for (int s = 1; s < FUT; ++s) {
            const int rb = (s - 1) & 1;
            GATES(rb)
            OUT_TILE(rb, ot[s - 1])
            ACTIV(s & 1)
            __syncthreads();
        }

        // ---------------- step 12: out only ----------------
        OUT_TILE(1, ot[FUT - 1])
        __syncthreads();

        // ---------------- coalesced flush: 384 floats ----------------
        if (tid < FUT * 32) {
            const float* otf = &ot[0][0][0];
            dout[((size_t)(tid >> 5) * N_AGENTS + A0) * 2 + (tid & 31)] = otf[tid];
        }
        // next preload writes hb[1] after the loop-top barrier;
        // next ot write (s=1 of next tile) is >=2 barriers away — safe
    }
#undef GATES
#undef OUT_TILE
#undef CORR
#undef CELLP
#undef ACTIV
}

extern "C" void kernel_launch(void* const* d_in, const int* in_sizes, int n_in,
                              void* d_out, int out_size, void* d_ws, size_t ws_size,
                              hipStream_t stream) {
    const float* obs  = (const float*)d_in[0];
    // d_in[1] (fut_traj_rel) is unused by the reference
    const float* h0   = (const float*)d_in[2];
    const float* Wih  = (const float*)d_in[3];
    const float* Whh  = (const float*)d_in[4];
    const float* bih  = (const float*)d_in[5];
    const float* bhh  = (const float*)d_in[6];
    const float* Wout = (const float*)d_in[7];
    const float* bo   = (const float*)d_in[8];
    float* out = (float*)d_out;

    dim3 grid(N_AGENTS / (AG * 16));   // 512 blocks of 512 threads -> 2 per CU
    lstm_dec_kernel<<<grid, 512, 0, stream>>>(obs, h0, Wih, Whh, bih, bhh, Wout, bo, out);
}